// Round 10
// baseline (1574.508 us; speedup 1.0000x reference)
//
#include <hip/hip_runtime.h>
#include <cmath>

#define T_STEPS 512
#define BATCH   64
#define ISZ     512
#define HSZ     512
#define EXN     32768   // u64 words per ring slot (64 batches x 512)

// ---------------------------------------------------------------------------
// Dual-path tagged-word exchange. One u64 = {tag=t+1 (hi32), h bits (lo32)}.
//  exF (ws[0..2*EXN))      fast copy:  store sc0 (write-THROUGH L1 -> shared
//                          L2), poll sc0 (bypass L1, read L2). Fast when
//                          producer+consumer share an XCD (bid&7 heuristic,
//                          PROVEN effective by R2's 7.4x FETCH cut).
//                          R8's version failed because its store was plain
//                          (write-back L1) -> never visible to sc0 loads.
//  exS (ws[2*EXN..4*EXN))  safety copy: agent-scope atomics via MALL --
//                          placement-independent, guarantees progress.
// Consumer accepts a word from EITHER copy with tag==t. Tags strictly
// increase, tag+payload share one u64 -> no stale-accept, no tearing.
// Depth-2 ring induction (proven R0-R4) unchanged by the second copy.
// ---------------------------------------------------------------------------
__device__ __forceinline__ void stF(unsigned long long* p, unsigned long long v) {
    asm volatile("global_store_dwordx2 %0, %1, off sc0" :: "v"(p), "v"(v) : "memory");
}
__device__ __forceinline__ void ld2F(unsigned long long& a, unsigned long long& b,
                                     const unsigned long long* p0,
                                     const unsigned long long* p1) {
    asm volatile("global_load_dwordx2 %0, %2, off sc0\n\t"
                 "global_load_dwordx2 %1, %3, off sc0\n\t"
                 "s_waitcnt vmcnt(0)"
                 : "=&v"(a), "=&v"(b) : "v"(p0), "v"(p1));
}

// Volatile-asm 16B load: pins weight panels (128 floats/thread budget; R6
// post-mortem: 256 aborts RA). Proven harmless R4/R5/R7/R8/R9.
__device__ __forceinline__ float4 ld_pin_f4(const float* p) {
    float4 v;
    asm volatile("global_load_dwordx4 %0, %1, off" : "=v"(v) : "v"(p));
    return v;
}

// ---------------------------------------------------------------------------
// 16-k-segment dot for 4 output rows x 2 batches, merging butterfly over the
// 32 ksegs (lane bits 0..4): 9 shfls. Lane kseg<8 ends with the full dot for
// row=((kseg>>1)&1)+2*((kseg>>2)&1), b=kseg&1. (R4-proven, 1020 us kernel.)
// LDS layout: float4[base + kseg*5 + i] (5-f4 slot pad).
// ---------------------------------------------------------------------------
__device__ __forceinline__ float dot16_fold(const float4 (&W)[4][4],
                                            const float4* __restrict__ src,
                                            int parbase4, int kseg) {
    const float4* s0 = src + parbase4 + kseg * 5;   // batch 0
    const float4* s1 = s0 + 160;                    // batch 1
    float A0 = 0.f, A1 = 0.f, A2 = 0.f, A3 = 0.f;
    float B0 = 0.f, B1 = 0.f, B2 = 0.f, B3 = 0.f;
    #pragma unroll
    for (int i = 0; i < 4; ++i) {
        const float4 h0 = s0[i];
        const float4 h1 = s1[i];
        const float4 w0 = W[0][i], w1 = W[1][i], w2 = W[2][i], w3 = W[3][i];
        A0 = fmaf(w0.x, h0.x, A0); A0 = fmaf(w0.y, h0.y, A0);
        A0 = fmaf(w0.z, h0.z, A0); A0 = fmaf(w0.w, h0.w, A0);
        A1 = fmaf(w1.x, h0.x, A1); A1 = fmaf(w1.y, h0.y, A1);
        A1 = fmaf(w1.z, h0.z, A1); A1 = fmaf(w1.w, h0.w, A1);
        A2 = fmaf(w2.x, h0.x, A2); A2 = fmaf(w2.y, h0.y, A2);
        A2 = fmaf(w2.z, h0.z, A2); A2 = fmaf(w2.w, h0.w, A2);
        A3 = fmaf(w3.x, h0.x, A3); A3 = fmaf(w3.y, h0.y, A3);
        A3 = fmaf(w3.z, h0.z, A3); A3 = fmaf(w3.w, h0.w, A3);
        B0 = fmaf(w0.x, h1.x, B0); B0 = fmaf(w0.y, h1.y, B0);
        B0 = fmaf(w0.z, h1.z, B0); B0 = fmaf(w0.w, h1.w, B0);
        B1 = fmaf(w1.x, h1.x, B1); B1 = fmaf(w1.y, h1.y, B1);
        B1 = fmaf(w1.z, h1.z, B1); B1 = fmaf(w1.w, h1.w, B1);
        B2 = fmaf(w2.x, h1.x, B2); B2 = fmaf(w2.y, h1.y, B2);
        B2 = fmaf(w2.z, h1.z, B2); B2 = fmaf(w2.w, h1.w, B2);
        B3 = fmaf(w3.x, h1.x, B3); B3 = fmaf(w3.y, h1.y, B3);
        B3 = fmaf(w3.z, h1.z, B3); B3 = fmaf(w3.w, h1.w, B3);
    }
    const bool sb0 = (kseg & 1) != 0;
    const bool sb1 = (kseg & 2) != 0;
    const bool sb2 = (kseg & 4) != 0;
    const float u0 = (sb0 ? B0 : A0) + __shfl_xor(sb0 ? A0 : B0, 1, 64);
    const float u1 = (sb0 ? B1 : A1) + __shfl_xor(sb0 ? A1 : B1, 1, 64);
    const float u2 = (sb0 ? B2 : A2) + __shfl_xor(sb0 ? A2 : B2, 1, 64);
    const float u3 = (sb0 ? B3 : A3) + __shfl_xor(sb0 ? A3 : B3, 1, 64);
    const float w01 = (sb1 ? u1 : u0) + __shfl_xor(sb1 ? u0 : u1, 2, 64);
    const float w23 = (sb1 ? u3 : u2) + __shfl_xor(sb1 ? u2 : u3, 2, 64);
    float z = (sb2 ? w23 : w01) + __shfl_xor(sb2 ? w01 : w23, 4, 64);
    z += __shfl_xor(z, 8, 64);
    z += __shfl_xor(z, 16, 64);
    return z;
}

// ---------------------------------------------------------------------------
// Fused RNN: R4's proven 1020us skeleton (256 WGs = 32 pairs x 8 slices,
// 512 thr, 1 WG/CU, thread owns 4 rows x 16 k x 2 batches, weights pinned,
// parity LDS, ONE barrier/step, both polls in flight together, in-loop xw)
// with ONLY the exchange upgraded to dual-path (sc0-L2 fast + MALL safety).
// R9's batch-split (two blocking detects/step) is reverted.
// ---------------------------------------------------------------------------
__global__ __launch_bounds__(512, 2) void rnn_fused(const float* __restrict__ x,
                                                    const float* __restrict__ wih,
                                                    const float* __restrict__ whh,
                                                    float* __restrict__ out,
                                                    unsigned long long* __restrict__ ex) {
    __shared__ __align__(16) float hls[2560];   // [2 par][2 b][32 kseg][5 f4]
    __shared__ __align__(16) float xss[2560];   // same layout, x rows
    const float4* hl4 = (const float4*)hls;
    const float4* xs4 = (const float4*)xss;

    const int tid  = threadIdx.x;
    const int bid  = blockIdx.x;
    const int xcd  = bid & 7;             // XCD under round-robin dispatch
    const int ib   = bid >> 3;            // 0..31 within XCD
    const int p    = xcd * 4 + (ib & 3);  // batch pair (8 WGs co-XCD heuristic,
    const int g    = ib >> 2;             //  proven by R2's FETCH 7.4x cut)
    const int kseg = tid & 31;
    const int jg   = tid >> 5;
    const int jb   = g * 64 + jg * 4;

    // ---- weight micro-panels: 4 rows x 16 k of W_hh and W_ih (128 f32) ----
    float4 wh[4][4], wi[4][4];
    #pragma unroll
    for (int r = 0; r < 4; ++r) {
        const float* hr = whh + (size_t)(jb + r) * HSZ + kseg * 16;
        const float* ir = wih + (size_t)(jb + r) * ISZ + kseg * 16;
        #pragma unroll
        for (int i = 0; i < 4; ++i) {
            wh[r][i] = ld_pin_f4(hr + 4 * i);
            wi[r][i] = ld_pin_f4(ir + 4 * i);
        }
    }
    asm volatile("s_waitcnt vmcnt(0)" ::: "memory");
    __builtin_amdgcn_sched_barrier(0);

    // exchange pointers: fast copies at +0, safety copies at +2*EXN
    unsigned long long* exf0 = ex + (size_t)(2 * p + 0) * 512 + tid;
    unsigned long long* exf1 = ex + (size_t)(2 * p + 1) * 512 + tid;

    // hl scatter offset for polled word k=tid (float idx; b=1 adds 640)
    const int whf = (tid >> 4) * 20 + ((tid >> 2) & 3) * 4 + (tid & 3);

    // x staging role: thread covers (bx, io..io+1), coalesced float2
    const int bx = tid >> 8;
    const int io = (tid & 255) * 2;
    const int xf = bx * 640 + (io >> 4) * 20 + ((io >> 2) & 3) * 4 + (io & 3);
    const float* xsrc = x + (size_t)(2 * p + bx) * ISZ + io;

    // designated-lane roles (valid for kseg<8)
    const int row  = ((kseg >> 1) & 1) + 2 * ((kseg >> 2) & 1);
    const int br   = kseg & 1;
    const int outj = jb + row;
    const int outb = 2 * p + br;
    float* outp = out + (size_t)outb * HSZ + outj;                 // + t*B*H
    unsigned long long* exfself = ex + (size_t)outb * 512 + outj;  // + slot*EXN

    // ---- prologue: stage x(0) (par 0), compute xw(0) ----
    {
        const float2 v = *(const float2*)xsrc;
        *(float2*)&xss[xf] = v;
    }
    __syncthreads();
    float xwv = dot16_fold(wi, xs4, 0, kseg);

    for (int t = 0; t < T_STEPS; ++t) {
        const int  parh4 = (t & 1) * 320;          // f4 base for hls
        const bool havex = (t < T_STEPS - 1);

        // issue x(t+1) prefetch early: HBM latency hides under the poll
        float2 xv;
        if (havex) xv = *(const float2*)(xsrc + (size_t)(t + 1) * (BATCH * ISZ));

        if (t > 0) {
            const size_t soff = (size_t)((t - 1) & 1) * EXN;
            const unsigned long long* f0 = exf0 + soff;
            const unsigned long long* f1 = exf1 + soff;
            unsigned long long v0, v1;
            ld2F(v0, v1, f0, f1);                  // first probe (fast L2 path)
            bool ok0 = ((unsigned)(v0 >> 32) == (unsigned)t);
            bool ok1 = ((unsigned)(v1 >> 32) == (unsigned)t);
            int it = 0;
            while (!(ok0 && ok1)) {
                ++it;
                unsigned long long w0, w1;
                ld2F(w0, w1, f0, f1);
                if (!ok0 && (unsigned)(w0 >> 32) == (unsigned)t) { v0 = w0; ok0 = true; }
                if (!ok1 && (unsigned)(w1 >> 32) == (unsigned)t) { v1 = w1; ok1 = true; }
                if (!(ok0 && ok1) && (it & 3) == 3) {
                    // placement-independent safety net (MALL copy) + backoff
                    if (!ok0) {
                        unsigned long long s = __hip_atomic_load(f0 + 2 * (size_t)EXN,
                            __ATOMIC_RELAXED, __HIP_MEMORY_SCOPE_AGENT);
                        if ((unsigned)(s >> 32) == (unsigned)t) { v0 = s; ok0 = true; }
                    }
                    if (!ok1) {
                        unsigned long long s = __hip_atomic_load(f1 + 2 * (size_t)EXN,
                            __ATOMIC_RELAXED, __HIP_MEMORY_SCOPE_AGENT);
                        if ((unsigned)(s >> 32) == (unsigned)t) { v1 = s; ok1 = true; }
                    }
                    __builtin_amdgcn_s_sleep(1);
                }
            }
            union { unsigned u; float f; } c0, c1;
            c0.u = (unsigned)v0; c1.u = (unsigned)v1;
            hls[parh4 * 4 + whf]       = c0.f;     // batch 0
            hls[parh4 * 4 + 640 + whf] = c1.f;     // batch 1
        }
        if (havex) *(float2*)&xss[((t + 1) & 1) * 1280 + xf] = xv;
        __syncthreads();                           // single barrier per step

        float acc = 0.f;
        if (t > 0)
            acc = dot16_fold(wh, hl4, parh4, kseg);

        if (kseg < 8) {                            // 8 designated lanes / 32
            const float a2 = acc + xwv;
            const float e  = __expf(2.f * a2);     // tanh = (e-1)/(e+1)
            const float hv = 1.f - 2.f / (e + 1.f);
            if (havex) {
                const size_t so = (size_t)(t & 1) * EXN;
                union { float f; unsigned u; } c; c.f = hv;
                const unsigned long long v =
                    ((unsigned long long)(unsigned)(t + 1) << 32) | c.u;
                stF(exfself + so, v);              // fast: through L1 into L2
                __hip_atomic_store(exfself + so + 2 * (size_t)EXN, v,
                                   __ATOMIC_RELAXED, __HIP_MEMORY_SCOPE_AGENT);
            }
            outp[(size_t)t * (BATCH * HSZ)] = hv;  // out store AFTER ex wire-up
            if (!havex)
                out[(size_t)T_STEPS * BATCH * HSZ + (size_t)outb * HSZ + outj] = hv;
        }

        // xw(t+1): independent of the exchange -> fills the propagation window
        if (havex)
            xwv = dot16_fold(wi, xs4, ((t + 1) & 1) * 320, kseg);
    }
}

// ---------------------------------------------------------------------------
extern "C" void kernel_launch(void* const* d_in, const int* in_sizes, int n_in,
                              void* d_out, int out_size, void* d_ws, size_t ws_size,
                              hipStream_t stream) {
    (void)in_sizes; (void)n_in; (void)out_size; (void)ws_size;
    const float* x   = (const float*)d_in[0];   // (512,64,512)
    const float* wih = (const float*)d_in[1];   // (512,512)
    const float* whh = (const float*)d_in[2];   // (512,512)
    float*       out = (float*)d_out;           // h_all (T,B,H) ++ h_last (B,H)
    unsigned long long* ex = (unsigned long long*)d_ws;   // 4*EXN u64 = 1 MB

    // zero BOTH exchange regions (fast + safety); harness poisons d_ws.
    (void)hipMemsetAsync(d_ws, 0, 4 * EXN * sizeof(unsigned long long), stream);

    hipLaunchKernelGGL(rnn_fused, dim3(256), dim3(512), 0, stream,
                       x, wih, whh, out, ex);
}

// Round 11
// 1049.276 us; speedup vs baseline: 1.5006x; 1.5006x over previous
//
#include <hip/hip_runtime.h>
#include <cmath>

#define T_STEPS 512
#define BATCH   64
#define ISZ     512
#define HSZ     512
#define EXN     32768   // u64 words per ring slot (64 batches x 512)

// ---------------------------------------------------------------------------
// Tagged-word exchange (proven protocol, R4 = 1020us best): one agent-scope
// atomic u64 = {tag=t+1 (hi32), h bits (lo32)}. R8/R10 proved plain/sc0
// "fast path" stores are NOT promptly visible; agent atomics are the floor.
// ---------------------------------------------------------------------------
__device__ __forceinline__ void ex_store(unsigned long long* w, float h, unsigned tag) {
    union { float f; unsigned u; } c; c.f = h;
    const unsigned long long v = ((unsigned long long)tag << 32) | (unsigned long long)c.u;
    __hip_atomic_store(w, v, __ATOMIC_RELAXED, __HIP_MEMORY_SCOPE_AGENT);
}

// Volatile-asm 16B load: pins weight panels (128 floats/thread budget; R6:
// 256 aborts RA). Proven harmless R4-R10.
__device__ __forceinline__ float4 ld_pin_f4(const float* p) {
    float4 v;
    asm volatile("global_load_dwordx4 %0, %1, off" : "=v"(v) : "v"(p));
    return v;
}

// ---------------------------------------------------------------------------
// 16-k-segment dot for 4 output rows x 2 batches, merging butterfly over the
// 32 ksegs (lane bits 0..4): 9 shfls. Lane kseg<8 ends with the full dot for
// row=((kseg>>1)&1)+2*((kseg>>2)&1), b=kseg&1. BYTE-IDENTICAL to the R4
// 1020us kernel. LDS layout: float4[base + kseg*5 + i] (5-f4 slot pad).
// ---------------------------------------------------------------------------
__device__ __forceinline__ float dot16_fold(const float4 (&W)[4][4],
                                            const float4* __restrict__ src,
                                            int parbase4, int kseg) {
    const float4* s0 = src + parbase4 + kseg * 5;   // batch 0
    const float4* s1 = s0 + 160;                    // batch 1
    float A0 = 0.f, A1 = 0.f, A2 = 0.f, A3 = 0.f;
    float B0 = 0.f, B1 = 0.f, B2 = 0.f, B3 = 0.f;
    #pragma unroll
    for (int i = 0; i < 4; ++i) {
        const float4 h0 = s0[i];
        const float4 h1 = s1[i];
        const float4 w0 = W[0][i], w1 = W[1][i], w2 = W[2][i], w3 = W[3][i];
        A0 = fmaf(w0.x, h0.x, A0); A0 = fmaf(w0.y, h0.y, A0);
        A0 = fmaf(w0.z, h0.z, A0); A0 = fmaf(w0.w, h0.w, A0);
        A1 = fmaf(w1.x, h0.x, A1); A1 = fmaf(w1.y, h0.y, A1);
        A1 = fmaf(w1.z, h0.z, A1); A1 = fmaf(w1.w, h0.w, A1);
        A2 = fmaf(w2.x, h0.x, A2); A2 = fmaf(w2.y, h0.y, A2);
        A2 = fmaf(w2.z, h0.z, A2); A2 = fmaf(w2.w, h0.w, A2);
        A3 = fmaf(w3.x, h0.x, A3); A3 = fmaf(w3.y, h0.y, A3);
        A3 = fmaf(w3.z, h0.z, A3); A3 = fmaf(w3.w, h0.w, A3);
        B0 = fmaf(w0.x, h1.x, B0); B0 = fmaf(w0.y, h1.y, B0);
        B0 = fmaf(w0.z, h1.z, B0); B0 = fmaf(w0.w, h1.w, B0);
        B1 = fmaf(w1.x, h1.x, B1); B1 = fmaf(w1.y, h1.y, B1);
        B1 = fmaf(w1.z, h1.z, B1); B1 = fmaf(w1.w, h1.w, B1);
        B2 = fmaf(w2.x, h1.x, B2); B2 = fmaf(w2.y, h1.y, B2);
        B2 = fmaf(w2.z, h1.z, B2); B2 = fmaf(w2.w, h1.w, B2);
        B3 = fmaf(w3.x, h1.x, B3); B3 = fmaf(w3.y, h1.y, B3);
        B3 = fmaf(w3.z, h1.z, B3); B3 = fmaf(w3.w, h1.w, B3);
    }
    const bool sb0 = (kseg & 1) != 0;
    const bool sb1 = (kseg & 2) != 0;
    const bool sb2 = (kseg & 4) != 0;
    const float u0 = (sb0 ? B0 : A0) + __shfl_xor(sb0 ? A0 : B0, 1, 64);
    const float u1 = (sb0 ? B1 : A1) + __shfl_xor(sb0 ? A1 : B1, 1, 64);
    const float u2 = (sb0 ? B2 : A2) + __shfl_xor(sb0 ? A2 : B2, 1, 64);
    const float u3 = (sb0 ? B3 : A3) + __shfl_xor(sb0 ? A3 : B3, 1, 64);
    const float w01 = (sb1 ? u1 : u0) + __shfl_xor(sb1 ? u0 : u1, 2, 64);
    const float w23 = (sb1 ? u3 : u2) + __shfl_xor(sb1 ? u2 : u3, 2, 64);
    float z = (sb2 ? w23 : w01) + __shfl_xor(sb2 ? w01 : w23, 4, 64);
    z += __shfl_xor(z, 8, 64);
    z += __shfl_xor(z, 16, 64);
    return z;
}

// ---------------------------------------------------------------------------
// Fused RNN, R4 protocol at 2 WGs/CU for hardware TLP stall-hiding.
// 512 WGs = 32 pairs x 16 j-slices (32 j), 256 threads (4 waves), 2 WGs/CU
// (guaranteed: launch_bounds(256,2) caps 256 VGPR; 8 waves, 40KB LDS per CU).
// Co-located WGs belong to different pair-clusters with INDEPENDENT latency
// chains: while one spins in its poll (s_sleep yields issue slots), the
// other computes -- the anti-phasing R5/R9 tried manually (and serialized),
// done by the CU scheduler. Per-thread work/protocol identical to R4:
// 4 rows x 16 k x 2 batches, 128 pinned weight floats, one barrier/step,
// both batches' polls in one detect point (now 4 words/thread), parity LDS.
// ---------------------------------------------------------------------------
__global__ __launch_bounds__(256, 2) void rnn_fused(const float* __restrict__ x,
                                                    const float* __restrict__ wih,
                                                    const float* __restrict__ whh,
                                                    float* __restrict__ out,
                                                    unsigned long long* __restrict__ ex) {
    __shared__ __align__(16) float hls[2560];   // [2 par][2 b][32 kseg][5 f4]
    __shared__ __align__(16) float xss[2560];   // same layout, x rows
    const float4* hl4 = (const float4*)hls;
    const float4* xs4 = (const float4*)xss;

    const int tid  = threadIdx.x;         // 0..255
    const int bid  = blockIdx.x;          // 0..511
    const int xcd  = bid & 7;             // XCD under round-robin dispatch
    const int ib   = bid >> 3;            // 0..63 within XCD
    const int p    = xcd * 4 + (ib & 3);  // batch pair (cluster co-XCD heur.)
    const int g    = ib >> 2;             // j-slice 0..15 (32 j each)
    const int kseg = tid & 31;            // 16-wide k segment
    const int jg   = tid >> 5;            // 0..7 -> 4 j rows each
    const int jb   = g * 32 + jg * 4;

    // ---- weight micro-panels: 4 rows x 16 k of W_hh and W_ih (128 f32) ----
    float4 wh[4][4], wi[4][4];
    #pragma unroll
    for (int r = 0; r < 4; ++r) {
        const float* hr = whh + (size_t)(jb + r) * HSZ + kseg * 16;
        const float* ir = wih + (size_t)(jb + r) * ISZ + kseg * 16;
        #pragma unroll
        for (int i = 0; i < 4; ++i) {
            wh[r][i] = ld_pin_f4(hr + 4 * i);
            wi[r][i] = ld_pin_f4(ir + 4 * i);
        }
    }
    asm volatile("s_waitcnt vmcnt(0)" ::: "memory");
    __builtin_amdgcn_sched_barrier(0);

    // poll pointers: 4 words/thread = {b0,b1} x {k=tid, k=tid+256}
    unsigned long long* ex00 = ex + (size_t)(2 * p + 0) * 512 + tid;        // b0 lo
    unsigned long long* ex01 = ex00 + 256;                                  // b0 hi
    unsigned long long* ex10 = ex + (size_t)(2 * p + 1) * 512 + tid;        // b1 lo
    unsigned long long* ex11 = ex10 + 256;                                  // b1 hi

    // hl scatter offsets: whf(k) for k=tid; k=tid+256 -> +320 floats.
    const int whf = (tid >> 4) * 20 + ((tid >> 2) & 3) * 4 + (tid & 3);

    // x staging role: thread covers (bx = tid>>7, f4 idx = tid&127)
    const int bx  = tid >> 7;
    const int idx = tid & 127;
    const int xf4 = bx * 160 + (idx >> 2) * 5 + (idx & 3);
    const float* xsrc = x + (size_t)(2 * p + bx) * ISZ + idx * 4;

    // designated-lane roles (valid for kseg<8)
    const int row  = ((kseg >> 1) & 1) + 2 * ((kseg >> 2) & 1);
    const int br   = kseg & 1;
    const int outj = jb + row;
    const int outb = 2 * p + br;
    float* outp = out + (size_t)outb * HSZ + outj;                 // + t*B*H
    unsigned long long* exself = ex + (size_t)outb * 512 + outj;   // + slot*EXN

    // ---- prologue: stage x(0) (par 0), compute xw(0) ----
    ((float4*)xss)[xf4] = *(const float4*)xsrc;
    __syncthreads();
    float xwv = dot16_fold(wi, xs4, 0, kseg);

    for (int t = 0; t < T_STEPS; ++t) {
        const int  parh4 = (t & 1) * 320;          // f4 base for hls
        const bool havex = (t < T_STEPS - 1);

        // issue x(t+1) prefetch early: HBM latency hides under the poll
        float4 xv;
        if (havex) xv = *(const float4*)(xsrc + (size_t)(t + 1) * (BATCH * ISZ));

        if (t > 0) {
            const size_t soff = (size_t)((t - 1) & 1) * EXN;
            unsigned long long v00 = __hip_atomic_load(ex00 + soff, __ATOMIC_RELAXED,
                                                       __HIP_MEMORY_SCOPE_AGENT);
            unsigned long long v01 = __hip_atomic_load(ex01 + soff, __ATOMIC_RELAXED,
                                                       __HIP_MEMORY_SCOPE_AGENT);
            unsigned long long v10 = __hip_atomic_load(ex10 + soff, __ATOMIC_RELAXED,
                                                       __HIP_MEMORY_SCOPE_AGENT);
            unsigned long long v11 = __hip_atomic_load(ex11 + soff, __ATOMIC_RELAXED,
                                                       __HIP_MEMORY_SCOPE_AGENT);
            while ((unsigned)(v00 >> 32) != (unsigned)t ||
                   (unsigned)(v01 >> 32) != (unsigned)t ||
                   (unsigned)(v10 >> 32) != (unsigned)t ||
                   (unsigned)(v11 >> 32) != (unsigned)t) {
                __builtin_amdgcn_s_sleep(1);       // yields issue to co-WG
                v00 = __hip_atomic_load(ex00 + soff, __ATOMIC_RELAXED,
                                        __HIP_MEMORY_SCOPE_AGENT);
                v01 = __hip_atomic_load(ex01 + soff, __ATOMIC_RELAXED,
                                        __HIP_MEMORY_SCOPE_AGENT);
                v10 = __hip_atomic_load(ex10 + soff, __ATOMIC_RELAXED,
                                        __HIP_MEMORY_SCOPE_AGENT);
                v11 = __hip_atomic_load(ex11 + soff, __ATOMIC_RELAXED,
                                        __HIP_MEMORY_SCOPE_AGENT);
            }
            union { unsigned u; float f; } c;
            c.u = (unsigned)v00; hls[parh4 * 4 + whf]             = c.f;  // b0 lo
            c.u = (unsigned)v01; hls[parh4 * 4 + whf + 320]       = c.f;  // b0 hi
            c.u = (unsigned)v10; hls[parh4 * 4 + 640 + whf]       = c.f;  // b1 lo
            c.u = (unsigned)v11; hls[parh4 * 4 + 640 + whf + 320] = c.f;  // b1 hi
        }
        if (havex) ((float4*)xss)[((t + 1) & 1) * 320 + xf4] = xv;
        __syncthreads();                           // single barrier per step

        float acc = 0.f;
        if (t > 0)
            acc = dot16_fold(wh, hl4, parh4, kseg);

        if (kseg < 8) {                            // 8 designated lanes / 32
            const float a2 = acc + xwv;
            const float e  = __expf(2.f * a2);     // tanh = (e-1)/(e+1)
            const float hv = 1.f - 2.f / (e + 1.f);
            if (havex)
                ex_store(exself + (size_t)(t & 1) * EXN, hv, (unsigned)(t + 1));
            outp[(size_t)t * (BATCH * HSZ)] = hv;
            if (!havex)
                out[(size_t)T_STEPS * BATCH * HSZ + (size_t)outb * HSZ + outj] = hv;
        }

        // xw(t+1): independent of the exchange -> fills the propagation window
        if (havex)
            xwv = dot16_fold(wi, xs4, ((t + 1) & 1) * 320, kseg);
    }
}

// ---------------------------------------------------------------------------
extern "C" void kernel_launch(void* const* d_in, const int* in_sizes, int n_in,
                              void* d_out, int out_size, void* d_ws, size_t ws_size,
                              hipStream_t stream) {
    (void)in_sizes; (void)n_in; (void)out_size; (void)ws_size;
    const float* x   = (const float*)d_in[0];   // (512,64,512)
    const float* wih = (const float*)d_in[1];   // (512,512)
    const float* whh = (const float*)d_in[2];   // (512,512)
    float*       out = (float*)d_out;           // h_all (T,B,H) ++ h_last (B,H)
    unsigned long long* ex = (unsigned long long*)d_ws;   // 2*EXN u64 = 512 KB

    // zero the exchange tags (harness poisons d_ws each launch)
    (void)hipMemsetAsync(d_ws, 0, 2 * EXN * sizeof(unsigned long long), stream);

    hipLaunchKernelGGL(rnn_fused, dim3(512), dim3(256), 0, stream,
                       x, wih, whh, out, ex);
}